// Round 4
// baseline (76.914 us; speedup 1.0000x reference)
//
#include <hip/hip_runtime.h>
#include <hip/hip_bf16.h>

typedef __attribute__((ext_vector_type(8))) short bf16x8;
typedef __attribute__((ext_vector_type(4))) float f32x4;

__device__ __forceinline__ short f2bf(float f) {
    union { float f; unsigned u; } v; v.f = f;
    unsigned r = v.u + 0x7fffu + ((v.u >> 16) & 1u);
    return (short)(r >> 16);
}

#define KP    896   // K padded 784 -> 896 (7 * 128)
#define KSTEP 128   // A staging granularity (512 B contiguous per row per step)
#define LDA   136   // A LDS row stride in shorts (128 + 8 -> 272 B, 16B-aligned)
#define LDB   40    // B LDS row stride in shorts (32 + 8)
#define ABUFS (64 * LDA)
#define BBUFS (256 * LDB)

#define WAITL  asm volatile("s_waitcnt lgkmcnt(0)" ::: "memory")
#define SBAR   __builtin_amdgcn_s_barrier()

// ---------------- init: transpose/convert weights, pointer tables ----------------
__global__ void init_kernel(const float* __restrict__ W1, const float* __restrict__ W2,
                            const float* __restrict__ Wp, const float* __restrict__ bp,
                            const float* __restrict__ Wr1, const float* __restrict__ br1,
                            const float* __restrict__ Wr2, const float* __restrict__ br2,
                            short* __restrict__ w1t, short* __restrict__ w2t,
                            float* __restrict__ ptabs)
{
    int tid = blockIdx.x * blockDim.x + threadIdx.x;
    int stride = gridDim.x * blockDim.x;
    // coalesced read of W1 (row-major), scattered 2B store into w1t[n][k]
    for (int i = tid; i < 784 * 256; i += stride) {
        int k = i >> 8, n = i & 255;
        w1t[n * KP + k] = f2bf(W1[i]);
    }
    for (int i = tid; i < 256 * 112; i += stride) {    // zero-pad k in [784,896)
        int n = i / 112, k = 784 + (i % 112);
        w1t[n * KP + k] = 0;
    }
    for (int i = tid; i < 16 * 256; i += stride) {     // w2t[n][k] = W2[k][n], N padded to 16
        int n = i >> 8, k = i & 255;
        float v = (n < 10) ? W2[k * 10 + n] : 0.f;
        w2t[i] = f2bf(v);
    }
    if (blockIdx.x == 0 && threadIdx.x < 8) {          // pointer tables: 4 programs only
        int which = threadIdx.x >> 2, p = threadIdx.x & 3;
        const float* Wr = which ? Wr2 : Wr1;
        const float* br = which ? br2 : br1;
        float s[4];
        for (int q = 0; q < 4; q++) {
            float a = br[q];
            for (int j = 0; j < 16; j++) a += (Wp[p * 16 + j] + bp[j]) * Wr[j * 4 + q];
            s[q] = a;
        }
        float m = fmaxf(fmaxf(s[0], s[1]), fmaxf(s[2], s[3]));
        float e[4]; float tot = 0.f;
        for (int q = 0; q < 4; q++) { e[q] = __expf(s[q] - m); tot += e[q]; }
        for (int q = 0; q < 4; q++) ptabs[which * 16 + p * 4 + q] = e[q] / tot;
    }
}

// ---------------- fused main kernel ----------------
// 1024 blocks x 512 threads (8 waves, 2x4). Tile: 64 rows x 256 cols.
// A: K-step=128 (512 B contiguous per row per step), double-buffered.
// B: chunk=32k, reg-staged depth-2, double-buffered [256][40].
__global__ __launch_bounds__(512, 4) void fused_kernel(
    const float* __restrict__ g_in, const float* __restrict__ onehot,
    const float* __restrict__ b1g, const float* __restrict__ b2g,
    const short* __restrict__ w1t, const short* __restrict__ w2t,
    const float* __restrict__ ptabs, float* __restrict__ out)
{
    __shared__ __align__(16) char lds[79616];
    short* Abuf = (short*)lds;                  // 2 x 64 x 136 bf16 = 34816 B
    short* Bbuf = (short*)(lds + 34816);        // 2 x 256 x 40 bf16 = 40960 B (ends 75776)
    short* h1   = (short*)lds;                  // overlay: 64 x 264 bf16 = 33792 B
    float* probs = (float*)(lds + 75776);       // 64 x 10 f32 = 2560 B
    float* dist1 = (float*)(lds + 78336);       // 16 x 10 f32 = 640 B
    float* dist2 = (float*)(lds + 78976);       // 16 x 10 f32 = 640 B

    const int t = threadIdx.x;
    const int lane = t & 63, wave = t >> 6;
    const int l16 = lane & 15, lg = lane >> 4;
    const int wr = wave >> 2, wc = wave & 3;
    const int blk = blockIdx.x;

    // A staging: 8 threads/row, 64 B contiguous each -> 512 B/row/step
    const int arow = t >> 3, tr = t & 7;
    const float* gA = g_in + ((long)blk * 64 + arow) * 784 + tr * 16;
    // B staging: 2 threads/row (256 rows), 16 shorts each
    const int bn = t >> 1, bh = t & 1;
    const short* gB = w1t + bn * KP + bh * 16;

    f32x4 acc[2][4];
    #pragma unroll
    for (int mi = 0; mi < 2; mi++)
        #pragma unroll
        for (int ni = 0; ni < 4; ni++)
            acc[mi][ni] = (f32x4)0.f;

    f32x4 xA0, xA1, xA2, xA3;                   // A staging regs (16 floats = 64 B)
    bf16x8 yA0, yA1, yB0, yB1;                  // B staging reg sets (set0, set1)

    auto issueA = [&](int kt) {
        const float* p = gA + kt * KSTEP;
        bool v = (kt < 6) | (tr == 0);          // 16-float chunks: fully valid or fully pad
        if (v) { xA0 = *(const f32x4*)p; xA1 = *(const f32x4*)(p + 4);
                 xA2 = *(const f32x4*)(p + 8); xA3 = *(const f32x4*)(p + 12); }
        else   { xA0 = (f32x4)0.f; xA1 = (f32x4)0.f; xA2 = (f32x4)0.f; xA3 = (f32x4)0.f; }
    };
    auto writeA = [&](int kt) {
        bf16x8 a0, a1;
        a0[0]=f2bf(xA0[0]); a0[1]=f2bf(xA0[1]); a0[2]=f2bf(xA0[2]); a0[3]=f2bf(xA0[3]);
        a0[4]=f2bf(xA1[0]); a0[5]=f2bf(xA1[1]); a0[6]=f2bf(xA1[2]); a0[7]=f2bf(xA1[3]);
        a1[0]=f2bf(xA2[0]); a1[1]=f2bf(xA2[1]); a1[2]=f2bf(xA2[2]); a1[3]=f2bf(xA2[3]);
        a1[4]=f2bf(xA3[0]); a1[5]=f2bf(xA3[1]); a1[6]=f2bf(xA3[2]); a1[7]=f2bf(xA3[3]);
        short* w = Abuf + (kt & 1) * ABUFS + arow * LDA + tr * 16;
        *(bf16x8*)w = a0;
        *(bf16x8*)(w + 8) = a1;
    };
    auto issueB0 = [&](int c) {                 // chunk c -> reg set 0
        const short* p = gB + c * 32;
        yA0 = *(const bf16x8*)p; yA1 = *(const bf16x8*)(p + 8);
    };
    auto issueB1 = [&](int c) {                 // chunk c -> reg set 1
        const short* p = gB + c * 32;
        yB0 = *(const bf16x8*)p; yB1 = *(const bf16x8*)(p + 8);
    };
    auto writeB0 = [&](int c) {                 // set 0 -> LDS buf (c&1)
        short* w = Bbuf + (c & 1) * BBUFS + bn * LDB + bh * 16;
        *(bf16x8*)w = yA0; *(bf16x8*)(w + 8) = yA1;
    };
    auto writeB1 = [&](int c) {
        short* w = Bbuf + (c & 1) * BBUFS + bn * LDB + bh * 16;
        *(bf16x8*)w = yB0; *(bf16x8*)(w + 8) = yB1;
    };
    auto mfmaSub = [&](int abuf, int bbuf, int s) {
        const short* ab = Abuf + abuf * ABUFS;
        const short* bb = Bbuf + bbuf * BBUFS;
        bf16x8 aF[2], bF[4];
        #pragma unroll
        for (int mi = 0; mi < 2; mi++)
            aF[mi] = *(const bf16x8*)(ab + (wr * 32 + mi * 16 + l16) * LDA + s * 32 + lg * 8);
        #pragma unroll
        for (int ni = 0; ni < 4; ni++)
            bF[ni] = *(const bf16x8*)(bb + (wc * 64 + ni * 16 + l16) * LDB + lg * 8);
        #pragma unroll
        for (int mi = 0; mi < 2; mi++)
            #pragma unroll
            for (int ni = 0; ni < 4; ni++)
                acc[mi][ni] = __builtin_amdgcn_mfma_f32_16x16x32_bf16(aF[mi], bF[ni], acc[mi][ni], 0, 0, 0);
    };

    // ---- prologue: B(0),B(1) -> regs; A(0) -> regs; publish A(0)+B(0) ----
    issueB0(0); issueB1(1); issueA(0);
    writeB0(0);                                  // compiler inserts exact vmcnt waits
    writeA(0);
    WAITL; SBAR;

    // ---- steady: kt = 0..5, 4 sub-steps each (chunk c0 = 4*kt) ----
    for (int kt = 0; kt < 6; ++kt) {
        const int c0 = kt * 4, a = kt & 1;
        // sub 0
        issueB0(c0 + 2); issueA(kt + 1);
        mfmaSub(a, 0, 0);
        writeB1(c0 + 1);
        WAITL; SBAR;
        // sub 1
        issueB1(c0 + 3);
        mfmaSub(a, 1, 1);
        writeB0(c0 + 2);
        WAITL; SBAR;
        // sub 2
        issueB0(c0 + 4);
        mfmaSub(a, 0, 2);
        writeB1(c0 + 3);
        writeA(kt + 1);
        WAITL; SBAR;
        // sub 3
        issueB1(c0 + 5);
        mfmaSub(a, 1, 3);
        writeB0(c0 + 4);
        WAITL; SBAR;
    }
    // ---- peel: kt = 6 (c0 = 24, A buf 0) ----
    issueB0(26);
    mfmaSub(0, 0, 0);
    writeB1(25);
    WAITL; SBAR;
    issueB1(27);
    mfmaSub(0, 1, 1);
    writeB0(26);
    WAITL; SBAR;
    mfmaSub(0, 0, 2);
    writeB1(27);
    WAITL; SBAR;
    mfmaSub(0, 1, 3);
    WAITL; SBAR;                                 // all LDS reads retired -> safe to overlay

    // ---- epilogue 1: relu + bias -> h1 (bf16) in LDS ----
    #pragma unroll
    for (int mi = 0; mi < 2; mi++) {
        const int R = wr * 32 + mi * 16 + lg * 4;
        #pragma unroll
        for (int ni = 0; ni < 4; ni++) {
            const int N = wc * 64 + ni * 16 + l16;
            const float bias = b1g[N];
            #pragma unroll
            for (int j = 0; j < 4; j++) {
                float v = acc[mi][ni][j] + bias;
                h1[(R + j) * 264 + N] = f2bf(fmaxf(v, 0.f));
            }
        }
    }
    __syncthreads();

    // ---- GEMM2 (waves 0-3): logits = h1 @ W2 (+b2), wave w rows 16w..16w+15 ----
    if (wave < 4) {
        f32x4 acc2 = (f32x4)0.f;
        const short* h1r = h1 + (wave * 16 + l16) * 264 + lg * 8;
        const short* w2r = w2t + l16 * 256 + lg * 8;
        #pragma unroll
        for (int kk = 0; kk < 8; kk++) {
            bf16x8 a2 = *(const bf16x8*)(h1r + kk * 32);
            bf16x8 b2f = *(const bf16x8*)(w2r + kk * 32);
            acc2 = __builtin_amdgcn_mfma_f32_16x16x32_bf16(a2, b2f, acc2, 0, 0, 0);
        }
        // softmax(logits/0.1): C frag row = lg*4+j, col = l16
        const float b2v = (l16 < 10) ? b2g[l16] : 0.f;
        float pv[4], mx[4];
        #pragma unroll
        for (int j = 0; j < 4; j++) {
            pv[j] = (l16 < 10) ? (acc2[j] + b2v) * 10.f : -1e30f;
            mx[j] = pv[j];
        }
        #pragma unroll
        for (int off = 1; off < 16; off <<= 1)
            #pragma unroll
            for (int j = 0; j < 4; j++)
                mx[j] = fmaxf(mx[j], __shfl_xor(mx[j], off));
        float ex[4], sm[4];
        #pragma unroll
        for (int j = 0; j < 4; j++) { ex[j] = __expf(pv[j] - mx[j]); sm[j] = ex[j]; }
        #pragma unroll
        for (int off = 1; off < 16; off <<= 1)
            #pragma unroll
            for (int j = 0; j < 4; j++)
                sm[j] += __shfl_xor(sm[j], off);
        if (l16 < 10)
            #pragma unroll
            for (int j = 0; j < 4; j++)
                probs[(wave * 16 + lg * 4 + j) * 10 + l16] = ex[j] / sm[j];
    }
    __syncthreads();

    // ---- pointer mix: dist1/dist2 (16 samples x 10 digits) ----
    if (t < 160) {
        int s = t / 10, d = t - s * 10;
        const float* oh = onehot + ((long)blk * 16 + s) * 4;
        int pid = (int)(oh[1] + 2.f * oh[2] + 3.f * oh[3] + 0.5f);
        const float* p1t = ptabs + pid * 4;
        const float* p2t = ptabs + 16 + pid * 4;
        float d1 = 0.f, d2 = 0.f;
        #pragma unroll
        for (int p = 0; p < 4; p++) {
            float pr = probs[(s * 4 + p) * 10 + d];
            d1 += p1t[p] * pr;
            d2 += p2t[p] * pr;
        }
        dist1[s * 10 + d] = d1;
        dist2[s * 10 + d] = d2;
    }
    __syncthreads();

    // ---- conv (i+j==k symmetric: symmetrization is a no-op) + log ----
    if (t < 304) {
        int s = t / 19, k = t - s * 19;
        int ilo = k > 9 ? k - 9 : 0;
        int ihi = k < 9 ? k : 9;
        float sum = 0.f;
        for (int i = ilo; i <= ihi; i++)
            sum += dist1[s * 10 + i] * dist2[s * 10 + (k - i)];
        out[((long)blk * 16 + s) * 19 + k] = __logf(sum + 1e-10f);
    }
}

extern "C" void kernel_launch(void* const* d_in, const int* in_sizes, int n_in,
                              void* d_out, int out_size, void* d_ws, size_t ws_size,
                              hipStream_t stream)
{
    const float* grid   = (const float*)d_in[0];
    const float* onehot = (const float*)d_in[1];
    const float* W1  = (const float*)d_in[2];
    const float* b1  = (const float*)d_in[3];
    const float* W2  = (const float*)d_in[4];
    const float* b2  = (const float*)d_in[5];
    const float* Wp  = (const float*)d_in[6];
    const float* bp  = (const float*)d_in[7];
    const float* Wr1 = (const float*)d_in[8];
    const float* br1 = (const float*)d_in[9];
    const float* Wr2 = (const float*)d_in[10];
    const float* br2 = (const float*)d_in[11];
    float* out = (float*)d_out;

    short* w1t = (short*)d_ws;              // 256 x 896 bf16 = 458752 B
    short* w2t = w1t + 256 * KP;            // 16 x 256 bf16  = 8192 B
    float* ptabs = (float*)(w2t + 16 * 256);// 2 x 4 x 4 f32  = 128 B

    init_kernel<<<256, 256, 0, stream>>>(W1, W2, Wp, bp, Wr1, br1, Wr2, br2, w1t, w2t, ptabs);

    const int B = in_sizes[1] / 4;          // 16384
    const int nblk = (B * 4) / 64;          // 1024
    fused_kernel<<<nblk, 512, 0, stream>>>(grid, onehot, b1, b2, w1t, w2t, ptabs, out);
}